// Round 5
// baseline (145.847 us; speedup 1.0000x reference)
//
#include <hip/hip_runtime.h>

typedef __bf16 bf16x8 __attribute__((ext_vector_type(8)));
typedef float f32x4 __attribute__((ext_vector_type(4)));
typedef unsigned int u32;

constexpr int Bc = 2, Sc = 2048, Hc = 16, Dc = 64;
constexpr int QBLK = 64, KVBLK = 64;
constexpr int NT = Sc / QBLK;          // 32 q-tiles
constexpr int ROWSTR = 3 * Hc * Dc;    // 3072 floats between consecutive s
constexpr float QSCALE = 0.125f * 1.4426950408889634f;  // 1/sqrt(D) * log2e

// MFMA f32_16x16x32_bf16 layouts (learn_hip m89/m97):
//   A[m][k]: lane l, elem j -> m = l&15,        k = 8*(l>>4) + j
//   B[k][n]: lane l, elem j -> k = 8*(l>>4)+j,  n = l&15
//   C/D[m][n]: lane l, reg r -> m = (l>>4)*4+r, n = l&15

static __device__ __forceinline__ u32 pack2(float a, float b) {
  unsigned short x = __builtin_bit_cast(unsigned short, (__bf16)a);
  unsigned short y = __builtin_bit_cast(unsigned short, (__bf16)b);
  return (u32)x | ((u32)y << 16);
}

__global__ __launch_bounds__(256, 2)
void fattn_kernel(const float* __restrict__ qkv, float* __restrict__ out) {
  // XCD-aware bijective swizzle (512 blocks, 512 % 8 == 0)
  const int id = blockIdx.x + blockIdx.y * gridDim.x;   // 0..511
  const int swz = (id & 7) * 64 + (id >> 3);
  const int xlow = swz & 15;            // 0..15
  const int xhigh = NT - 1 - xlow;      // 31..16 (constant 33 tile-steps/block)
  const int bh = swz >> 4;
  const int b = bh >> 4, h = bh & 15;

  const int tid = threadIdx.x;
  const int wave = tid >> 6;
  const int lane = tid & 63;
  const int lg = lane >> 4;             // 0..3
  const int li = lane & 15;             // 0..15

  const float* qp = qkv + (size_t)b * Sc * ROWSTR + h * Dc;
  const float* kp = qp + Hc * Dc;
  const float* vp = qp + 2 * Hc * Dc;

  __shared__ __align__(16) char k_s[2][KVBLK * Dc * 2];   // [kv][d] bf16, XOR-swz
  __shared__ __align__(16) char v_s[2][Dc * KVBLK * 2];   // V^T [d][kv] bf16, XOR-swz
  __shared__ __align__(16) char p_s[4][2][16 * KVBLK * 2];
  char* pw_H = &p_s[wave][0][0];
  char* pw_L = &p_s[wave][1][0];

  // ---- Q fragments for both q-tiles, pre-scaled (1/sqrt(D) * log2e) ----
  const int qwL = xlow * QBLK + wave * 16;
  const int qwH = xhigh * QBLK + wave * 16;
  bf16x8 qfL[2], qfH[2];
  {
    const float* qrL = qp + (size_t)(qwL + li) * ROWSTR + 8 * lg;
    const float* qrH = qp + (size_t)(qwH + li) * ROWSTR + 8 * lg;
#pragma unroll
    for (int fi = 0; fi < 2; ++fi) {
      f32x4 a0 = *(const f32x4*)(qrL + 32 * fi);
      f32x4 a1 = *(const f32x4*)(qrL + 32 * fi + 4);
      f32x4 b0 = *(const f32x4*)(qrH + 32 * fi);
      f32x4 b1 = *(const f32x4*)(qrH + 32 * fi + 4);
      bf16x8 qa, qb;
#pragma unroll
      for (int j = 0; j < 4; ++j) {
        qa[j] = (__bf16)(a0[j] * QSCALE); qa[j + 4] = (__bf16)(a1[j] * QSCALE);
        qb[j] = (__bf16)(b0[j] * QSCALE); qb[j + 4] = (__bf16)(b1[j] * QSCALE);
      }
      qfL[fi] = qa; qfH[fi] = qb;
    }
  }

  f32x4 oL[4], oH[4];
  float mLr[4], lLr[4], mHr[4], lHr[4];
#pragma unroll
  for (int n = 0; n < 4; ++n) { oL[n] = f32x4{0, 0, 0, 0}; oH[n] = f32x4{0, 0, 0, 0}; }
#pragma unroll
  for (int r = 0; r < 4; ++r) { mLr[r] = -1e30f; lLr[r] = 0.f; mHr[r] = -1e30f; lHr[r] = 0.f; }

  // ---- staging (T14 split): coalesced loads early, conflict-free LDS writes late ----
  f32x4 kr[4], vr[4];
  auto stage_load = [&](int kv0) {
#pragma unroll
    for (int it = 0; it < 2; ++it) {
      const int u = tid + it * 256, r = u >> 3, g = u & 7;
      const float* ks = kp + (size_t)(kv0 + r) * ROWSTR + g * 8;
      const float* vs = vp + (size_t)(kv0 + r) * ROWSTR + g * 8;
      kr[2 * it]     = *(const f32x4*)ks;
      kr[2 * it + 1] = *(const f32x4*)(ks + 4);
      vr[2 * it]     = *(const f32x4*)vs;
      vr[2 * it + 1] = *(const f32x4*)(vs + 4);
    }
  };
  auto stage_write = [&](char* kd, char* vd) {
#pragma unroll
    for (int it = 0; it < 2; ++it) {
      const int u = tid + it * 256, r = u >> 3, g = u & 7;
      bf16x8 kb;
#pragma unroll
      for (int j = 0; j < 4; ++j) {
        kb[j] = (__bf16)kr[2 * it][j]; kb[j + 4] = (__bf16)kr[2 * it + 1][j];
      }
      *(bf16x8*)(kd + ((r * 128 + g * 16) ^ ((r & 7) << 4))) = kb;

      // V^T: pair kv rows (r, r^1) via shfl_xor(8); even r keeps d 0..3 of its
      // octet, odd r keeps d 4..7. Rotate store order by g so simultaneous
      // stores spread d&7 across all banks (2-way max).
      const int odd = r & 1;
      f32x4 tmp = odd ? vr[2 * it] : vr[2 * it + 1];   // send half the partner needs
      f32x4 rcv;
#pragma unroll
      for (int j = 0; j < 4; ++j) rcv[j] = __shfl_xor(tmp[j], 8, 64);
      const int kvb2 = (r & ~1) * 2;
#pragma unroll
      for (int s = 0; s < 4; ++s) {
        const int dj = (s + g) & 3;
        const float lo = odd ? rcv[dj] : vr[2 * it][dj];       // kv even of pair
        const float hi = odd ? vr[2 * it + 1][dj] : rcv[dj];   // kv odd of pair
        const int d = 8 * g + 4 * odd + dj;
        *(u32*)(vd + ((d * 128 + kvb2) ^ ((d & 7) << 4))) = pack2(lo, hi);
      }
    }
  };

  // ---- one online-softmax + PV step for one q-tile ----
  auto tile_step = [&](const bf16x8 (&kf)[4][2], const bf16x8* qf, f32x4* oacc,
                       float* mrow, float* lrow, char* pw, const char* vt,
                       bool diag, int kv0, int qw) {
    f32x4 sacc[4];
#pragma unroll
    for (int n = 0; n < 4; ++n) sacc[n] = f32x4{0, 0, 0, 0};
    __builtin_amdgcn_s_setprio(1);
#pragma unroll
    for (int n = 0; n < 4; ++n)
#pragma unroll
      for (int fi = 0; fi < 2; ++fi)
        sacc[n] = __builtin_amdgcn_mfma_f32_16x16x32_bf16(qf[fi], kf[n][fi], sacc[n], 0, 0, 0);
    __builtin_amdgcn_s_setprio(0);

    if (diag) {
      const int qrow = qw + 4 * lg;
#pragma unroll
      for (int n = 0; n < 4; ++n)
#pragma unroll
        for (int r = 0; r < 4; ++r)
          if (kv0 + 16 * n + li > qrow + r) sacc[n][r] = -1e30f;
    }

    // row max (reduce over li within 16-lane groups)
    float pm[4];
#pragma unroll
    for (int r = 0; r < 4; ++r)
      pm[r] = fmaxf(fmaxf(sacc[0][r], sacc[1][r]), fmaxf(sacc[2][r], sacc[3][r]));
#pragma unroll
    for (int msk = 1; msk <= 8; msk <<= 1)
#pragma unroll
      for (int r = 0; r < 4; ++r)
        pm[r] = fmaxf(pm[r], __shfl_xor(pm[r], msk, 64));

    // T13 defer-rescale (log2 domain, THR=8)
    bool need = false;
#pragma unroll
    for (int r = 0; r < 4; ++r) need = need || (pm[r] > mrow[r] + 8.0f);
    if (__any(need)) {
#pragma unroll
      for (int r = 0; r < 4; ++r) {
        float mnew = fmaxf(mrow[r], pm[r]);
        float scl = __builtin_exp2f(mrow[r] - mnew);
        mrow[r] = mnew;
        lrow[r] *= scl;
#pragma unroll
        for (int n = 0; n < 4; ++n) oacc[n][r] *= scl;
      }
    }

    float lsum[4] = {0.f, 0.f, 0.f, 0.f};
#pragma unroll
    for (int n = 0; n < 4; ++n)
#pragma unroll
      for (int r = 0; r < 4; ++r) {
        float p = __builtin_exp2f(sacc[n][r] - mrow[r]);
        sacc[n][r] = p;
        lsum[r] += p;
      }
#pragma unroll
    for (int msk = 1; msk <= 8; msk <<= 1)
#pragma unroll
      for (int r = 0; r < 4; ++r)
        lsum[r] += __shfl_xor(lsum[r], msk, 64);
#pragma unroll
    for (int r = 0; r < 4; ++r) lrow[r] += lsum[r];

    // P store [q][kv] bf16 swizzled: pair kv (li, li^1) via shfl_xor(1),
    // even li writes q-rows {0,1}, odd li writes q-rows {2,3} of its lg group.
    // byte(q,kv) = q*128 + kv*2, kv = 16n + li  ->  base = 32n + (li&~1)*2.
    {
      const int oddli = li & 1;
      const int kvoff = (li & ~1) * 2;
      const int q0 = 4 * lg + 2 * oddli;
      const int sw0 = (q0 & 7) << 4;
      const int sw1 = ((q0 + 1) & 7) << 4;
#pragma unroll
      for (int n = 0; n < 4; ++n) {
        float t0 = oddli ? sacc[n][0] : sacc[n][2];
        float t1 = oddli ? sacc[n][1] : sacc[n][3];
        float r0 = __shfl_xor(t0, 1, 64);
        float r1 = __shfl_xor(t1, 1, 64);
        float lo0 = oddli ? r0 : sacc[n][0];
        float hi0 = oddli ? sacc[n][2] : r0;
        float lo1 = oddli ? r1 : sacc[n][1];
        float hi1 = oddli ? sacc[n][3] : r1;
        const int base = n * 32 + kvoff;           // FIX: was n*64 (2x, OOB)
        *(u32*)(pw + ((q0 * 128 + base) ^ sw0)) = pack2(lo0, hi0);
        *(u32*)(pw + (((q0 + 1) * 128 + base) ^ sw1)) = pack2(lo1, hi1);
      }
    }

    // PV from LDS (verified b128 swizzled reads)
#pragma unroll
    for (int ks = 0; ks < 2; ++ks) {
      const int pbyte = (li * 128 + (32 * ks + 8 * lg) * 2) ^ ((li & 7) << 4);
      bf16x8 pa = *(const bf16x8*)(pw + pbyte);
      __builtin_amdgcn_s_setprio(1);
#pragma unroll
      for (int n = 0; n < 4; ++n) {
        const int row = 16 * n + li;
        const int vbyte = (row * 128 + (32 * ks + 8 * lg) * 2) ^ ((row & 7) << 4);
        bf16x8 vb = *(const bf16x8*)(vt + vbyte);
        oacc[n] = __builtin_amdgcn_mfma_f32_16x16x32_bf16(pa, vb, oacc[n], 0, 0, 0);
      }
      __builtin_amdgcn_s_setprio(0);
    }
  };

  // ---- prologue ----
  stage_load(0);
  stage_write(k_s[0], v_s[0]);
  __syncthreads();

  int cur = 0;
  for (int t = 0; t <= xhigh; ++t) {
    const int kv0 = t * KVBLK;
    const bool have_next = (t < xhigh);
    if (have_next) stage_load(kv0 + KVBLK);   // issue early; latency hides under compute

    // K fragments from LDS, shared by H and L tiles
    const char* ksrc = k_s[cur];
    bf16x8 kf[4][2];
#pragma unroll
    for (int n = 0; n < 4; ++n) {
      const int krow = 16 * n + li;
      const int sw = (krow & 7) << 4;
#pragma unroll
      for (int fi = 0; fi < 2; ++fi)
        kf[n][fi] = *(const bf16x8*)(ksrc + ((krow * 128 + fi * 64 + lg * 16) ^ sw));
    }

    tile_step(kf, qfH, oH, mHr, lHr, pw_H, v_s[cur], t == xhigh, kv0, qwH);
    if (t <= xlow)
      tile_step(kf, qfL, oL, mLr, lLr, pw_L, v_s[cur], t == xlow, kv0, qwL);

    if (have_next) stage_write(k_s[cur ^ 1], v_s[cur ^ 1]);
    __syncthreads();
    cur ^= 1;
  }

  // ---- epilogue: normalize and store both q-tiles ----
#pragma unroll
  for (int r = 0; r < 4; ++r) {
    const float invH = 1.0f / lHr[r];
    const float invL = 1.0f / lLr[r];
    float* opH = out + ((size_t)(b * Sc + qwH + 4 * lg + r) * Hc + h) * Dc;
    float* opL = out + ((size_t)(b * Sc + qwL + 4 * lg + r) * Hc + h) * Dc;
#pragma unroll
    for (int n = 0; n < 4; ++n) {
      opH[16 * n + li] = oH[n][r] * invH;
      opL[16 * n + li] = oL[n][r] * invL;
    }
  }
}

extern "C" void kernel_launch(void* const* d_in, const int* in_sizes, int n_in,
                              void* d_out, int out_size, void* d_ws, size_t ws_size,
                              hipStream_t stream) {
  const float* qkv = (const float*)d_in[0];
  float* out = (float*)d_out;
  dim3 grid(NT / 2, Bc * Hc);   // (16, 32)
  fattn_kernel<<<grid, 256, 0, stream>>>(qkv, out);
}

// Round 6
// 91.175 us; speedup vs baseline: 1.5996x; 1.5996x over previous
//
#include <hip/hip_runtime.h>

typedef __bf16 bf16x8 __attribute__((ext_vector_type(8)));
typedef float f32x4 __attribute__((ext_vector_type(4)));
typedef unsigned int u32;

constexpr int Bc = 2, Sc = 2048, Hc = 16, Dc = 64;
constexpr int QBLK = 64, KVBLK = 64;
constexpr int NT = Sc / QBLK;          // 32 q-tiles
constexpr int ROWSTR = 3 * Hc * Dc;    // 3072 floats between consecutive s
constexpr float QSCALE = 0.125f * 1.4426950408889634f;  // 1/sqrt(D) * log2e

// MFMA f32_16x16x32_bf16 layouts (learn_hip m89/m97):
//   A[m][k]: lane l, elem j -> m = l&15,        k = 8*(l>>4) + j
//   B[k][n]: lane l, elem j -> k = 8*(l>>4)+j,  n = l&15
//   C/D[m][n]: lane l, reg r -> m = (l>>4)*4+r, n = l&15

// DPP cross-lane on the VALU pipe (no DS ops).
// row_ror:n = 0x120+n (rotate within 16-lane row); quad_perm[1,0,3,2] = 0xB1 (lane^1).
template <int CTRL>
static __device__ __forceinline__ float dppf(float x) {
  int xi = __builtin_bit_cast(int, x);
  return __builtin_bit_cast(float,
      __builtin_amdgcn_update_dpp(xi, xi, CTRL, 0xF, 0xF, false));
}
static __device__ __forceinline__ float redmax16(float x) {
  x = fmaxf(x, dppf<0x121>(x));
  x = fmaxf(x, dppf<0x122>(x));
  x = fmaxf(x, dppf<0x124>(x));
  x = fmaxf(x, dppf<0x128>(x));
  return x;  // all 16 lanes of the row hold the max
}
static __device__ __forceinline__ float redsum16(float x) {
  x += dppf<0x121>(x);
  x += dppf<0x122>(x);
  x += dppf<0x124>(x);
  x += dppf<0x128>(x);
  return x;
}

static __device__ __forceinline__ u32 pack2(float a, float b) {
  unsigned short x = __builtin_bit_cast(unsigned short, (__bf16)a);
  unsigned short y = __builtin_bit_cast(unsigned short, (__bf16)b);
  return (u32)x | ((u32)y << 16);
}

__global__ __launch_bounds__(256, 2)
void fattn_kernel(const float* __restrict__ qkv, float* __restrict__ out) {
  // XCD-aware bijective swizzle (512 blocks, 512 % 8 == 0)
  const int id = blockIdx.x + blockIdx.y * gridDim.x;   // 0..511
  const int swz = (id & 7) * 64 + (id >> 3);
  const int xlow = swz & 15;            // 0..15
  const int xhigh = NT - 1 - xlow;      // 31..16 (constant 33 tile-steps/block)
  const int bh = swz >> 4;
  const int b = bh >> 4, h = bh & 15;

  const int tid = threadIdx.x;
  const int wave = tid >> 6;
  const int lane = tid & 63;
  const int lg = lane >> 4;             // 0..3
  const int li = lane & 15;             // 0..15

  const float* qp = qkv + (size_t)b * Sc * ROWSTR + h * Dc;
  const float* kp = qp + Hc * Dc;
  const float* vp = qp + 2 * Hc * Dc;

  __shared__ __align__(16) char k_s[KVBLK * Dc * 2];   // [kv][d] bf16, XOR-swz
  __shared__ __align__(16) char v_s[Dc * KVBLK * 2];   // V^T [d][kv] bf16, XOR-swz
  __shared__ __align__(16) char p_s[4][16 * KVBLK * 2];
  char* pw = p_s[wave];

  // ---- Q fragments for both q-tiles, pre-scaled (1/sqrt(D) * log2e) ----
  const int qwL = xlow * QBLK + wave * 16;
  const int qwH = xhigh * QBLK + wave * 16;
  bf16x8 qfL[2], qfH[2];
  {
    const float* qrL = qp + (size_t)(qwL + li) * ROWSTR + 8 * lg;
    const float* qrH = qp + (size_t)(qwH + li) * ROWSTR + 8 * lg;
#pragma unroll
    for (int fi = 0; fi < 2; ++fi) {
      f32x4 a0 = *(const f32x4*)(qrL + 32 * fi);
      f32x4 a1 = *(const f32x4*)(qrL + 32 * fi + 4);
      f32x4 b0 = *(const f32x4*)(qrH + 32 * fi);
      f32x4 b1 = *(const f32x4*)(qrH + 32 * fi + 4);
      bf16x8 qa, qb;
#pragma unroll
      for (int j = 0; j < 4; ++j) {
        qa[j] = (__bf16)(a0[j] * QSCALE); qa[j + 4] = (__bf16)(a1[j] * QSCALE);
        qb[j] = (__bf16)(b0[j] * QSCALE); qb[j + 4] = (__bf16)(b1[j] * QSCALE);
      }
      qfL[fi] = qa; qfH[fi] = qb;
    }
  }

  f32x4 oL[4], oH[4];
  float mLr[4], lLr[4], mHr[4], lHr[4];
#pragma unroll
  for (int n = 0; n < 4; ++n) { oL[n] = f32x4{0, 0, 0, 0}; oH[n] = f32x4{0, 0, 0, 0}; }
#pragma unroll
  for (int r = 0; r < 4; ++r) { mLr[r] = -1e30f; lLr[r] = 0.f; mHr[r] = -1e30f; lHr[r] = 0.f; }

  bf16x8 kf[4][2], vf[4][2];

  // ---- one online-softmax + PV step for one q-tile (kf/vf shared via regs) ----
  auto tile_step = [&](const bf16x8 (&qf)[2], f32x4 (&oacc)[4],
                       float (&mrow)[4], float (&lrow)[4], bool diag, int kv0, int qw) {
    f32x4 sacc[4];
#pragma unroll
    for (int n = 0; n < 4; ++n) sacc[n] = f32x4{0, 0, 0, 0};
    __builtin_amdgcn_s_setprio(1);
#pragma unroll
    for (int n = 0; n < 4; ++n)
#pragma unroll
      for (int fi = 0; fi < 2; ++fi)
        sacc[n] = __builtin_amdgcn_mfma_f32_16x16x32_bf16(qf[fi], kf[n][fi], sacc[n], 0, 0, 0);
    __builtin_amdgcn_s_setprio(0);

    if (diag) {
      const int qrow = qw + 4 * lg;
#pragma unroll
      for (int n = 0; n < 4; ++n)
#pragma unroll
        for (int r = 0; r < 4; ++r)
          if (kv0 + 16 * n + li > qrow + r) sacc[n][r] = -1e30f;
    }

    // row max over kv (in-reg + DPP rotate reduction, VALU pipe)
    float pm[4];
#pragma unroll
    for (int r = 0; r < 4; ++r) {
      pm[r] = fmaxf(fmaxf(sacc[0][r], sacc[1][r]), fmaxf(sacc[2][r], sacc[3][r]));
      pm[r] = redmax16(pm[r]);
    }

    // T13 defer-rescale (log2 domain, THR=8)
    bool need = false;
#pragma unroll
    for (int r = 0; r < 4; ++r) need = need || (pm[r] > mrow[r] + 8.0f);
    if (__any(need)) {
#pragma unroll
      for (int r = 0; r < 4; ++r) {
        float mnew = fmaxf(mrow[r], pm[r]);
        float scl = __builtin_exp2f(mrow[r] - mnew);
        mrow[r] = mnew;
        lrow[r] *= scl;
#pragma unroll
        for (int n = 0; n < 4; ++n) oacc[n][r] *= scl;
      }
    }

#pragma unroll
    for (int r = 0; r < 4; ++r) {
      float s = 0.f;
#pragma unroll
      for (int n = 0; n < 4; ++n) {
        float p = __builtin_exp2f(sacc[n][r] - mrow[r]);
        sacc[n][r] = p;
        s += p;
      }
      lrow[r] += redsum16(s);
    }

    // P store [q][kv] bf16 swizzled: pair kv (li, li^1) via DPP quad_perm (lane^1).
    // byte(q,kv) = q*128 + kv*2, kv = 16n + li -> base = 32n + (li&~1)*2.
    {
      const int oddli = li & 1;
      const int kvoff = (li & ~1) * 2;
      const int q0 = 4 * lg + 2 * oddli;
      const int sw0 = (q0 & 7) << 4;
      const int sw1 = ((q0 + 1) & 7) << 4;
#pragma unroll
      for (int n = 0; n < 4; ++n) {
        float t0 = oddli ? sacc[n][0] : sacc[n][2];
        float t1 = oddli ? sacc[n][1] : sacc[n][3];
        float r0 = dppf<0xB1>(t0);   // lane^1
        float r1 = dppf<0xB1>(t1);
        float lo0 = oddli ? r0 : sacc[n][0];
        float hi0 = oddli ? sacc[n][2] : r0;
        float lo1 = oddli ? r1 : sacc[n][1];
        float hi1 = oddli ? sacc[n][3] : r1;
        const int base = n * 32 + kvoff;
        *(u32*)(pw + ((q0 * 128 + base) ^ sw0)) = pack2(lo0, hi0);
        *(u32*)(pw + (((q0 + 1) * 128 + base) ^ sw1)) = pack2(lo1, hi1);
      }
    }

    // PV: P from LDS (2 b128), V from shared register fragments
#pragma unroll
    for (int ks = 0; ks < 2; ++ks) {
      const int pbyte = (li * 128 + (32 * ks + 8 * lg) * 2) ^ ((li & 7) << 4);
      bf16x8 pa = *(const bf16x8*)(pw + pbyte);
      __builtin_amdgcn_s_setprio(1);
#pragma unroll
      for (int n = 0; n < 4; ++n)
        oacc[n] = __builtin_amdgcn_mfma_f32_16x16x32_bf16(pa, vf[n][ks], oacc[n], 0, 0, 0);
      __builtin_amdgcn_s_setprio(0);
    }
  };

  for (int t = 0; t <= xhigh; ++t) {
    const int kv0 = t * KVBLK;

    // ---- staging: coalesced loads, conflict-free LDS writes (DPP pairing) ----
#pragma unroll
    for (int it = 0; it < 2; ++it) {
      const int u = tid + it * 256, r = u >> 3, g = u & 7;
      const float* ks = kp + (size_t)(kv0 + r) * ROWSTR + g * 8;
      const float* vs = vp + (size_t)(kv0 + r) * ROWSTR + g * 8;
      f32x4 k0 = *(const f32x4*)ks;
      f32x4 k1 = *(const f32x4*)(ks + 4);
      f32x4 v0 = *(const f32x4*)vs;
      f32x4 v1 = *(const f32x4*)(vs + 4);
      bf16x8 kb;
#pragma unroll
      for (int j = 0; j < 4; ++j) { kb[j] = (__bf16)k0[j]; kb[j + 4] = (__bf16)k1[j]; }
      *(bf16x8*)(k_s + ((r * 128 + g * 16) ^ ((r & 7) << 4))) = kb;

      // V^T: pair kv rows (r, r^1) via DPP row_ror:8 (== lane^8 within 16-row);
      // even r keeps d 0..3 of its octet, odd r keeps d 4..7; rotate store
      // order by g so simultaneous stores spread d&7 across banks.
      const int odd = r & 1;
      f32x4 tmp = odd ? v0 : v1;   // send the half the partner needs
      f32x4 rcv;
#pragma unroll
      for (int j = 0; j < 4; ++j) rcv[j] = dppf<0x128>(tmp[j]);
      const int kvb2 = (r & ~1) * 2;
#pragma unroll
      for (int s = 0; s < 4; ++s) {
        const int dj = (s + g) & 3;
        const float lo = odd ? rcv[dj] : v0[dj];    // kv even of pair
        const float hi = odd ? v1[dj] : rcv[dj];    // kv odd of pair
        const int d = 8 * g + 4 * odd + dj;
        *(u32*)(v_s + ((d * 128 + kvb2) ^ ((d & 7) << 4))) = pack2(lo, hi);
      }
    }
    __syncthreads();

    // ---- K and V fragments once per iteration, shared by H and L ----
#pragma unroll
    for (int n = 0; n < 4; ++n) {
      const int krow = 16 * n + li;
      const int sw = (krow & 7) << 4;
#pragma unroll
      for (int fi = 0; fi < 2; ++fi) {
        kf[n][fi] = *(const bf16x8*)(k_s + ((krow * 128 + fi * 64 + lg * 16) ^ sw));
        vf[n][fi] = *(const bf16x8*)(v_s + ((krow * 128 + fi * 64 + lg * 16) ^ sw));
      }
    }

    tile_step(qfH, oH, mHr, lHr, t == xhigh, kv0, qwH);
    if (t <= xlow)
      tile_step(qfL, oL, mLr, lLr, t == xlow, kv0, qwL);

    __syncthreads();
  }

  // ---- epilogue: normalize and store both q-tiles ----
#pragma unroll
  for (int r = 0; r < 4; ++r) {
    const float invH = 1.0f / lHr[r];
    const float invL = 1.0f / lLr[r];
    float* opH = out + ((size_t)(b * Sc + qwH + 4 * lg + r) * Hc + h) * Dc;
    float* opL = out + ((size_t)(b * Sc + qwL + 4 * lg + r) * Hc + h) * Dc;
#pragma unroll
    for (int n = 0; n < 4; ++n) {
      opH[16 * n + li] = oH[n][r] * invH;
      opL[16 * n + li] = oL[n][r] * invL;
    }
  }
}

extern "C" void kernel_launch(void* const* d_in, const int* in_sizes, int n_in,
                              void* d_out, int out_size, void* d_ws, size_t ws_size,
                              hipStream_t stream) {
  const float* qkv = (const float*)d_in[0];
  float* out = (float*)d_out;
  dim3 grid(NT / 2, Bc * Hc);   // (16, 32)
  fattn_kernel<<<grid, 256, 0, stream>>>(qkv, out);
}